// Round 1
// baseline (31.145 us; speedup 1.0000x reference)
//
#include <hip/hip_runtime.h>

#define BLOCK 256

// tanh(x) = 1 - 2/(exp(2x)+1); exact at +-inf limits, ~1ulp-ish accuracy.
__device__ __forceinline__ float fast_tanh(float x) {
    float e = __expf(2.0f * x);
    return 1.0f - 2.0f * __builtin_amdgcn_rcpf(e + 1.0f);
}

// One Ry(ta) x Ry(tb) |00> -> matchgate(th, phi1, phi2) pair; returns <Zi>,<Zj>,<ZiZj>.
// ta,tb,th are the FULL angles (half-angle applied inside); phi1,phi2 used as-is.
__device__ __forceinline__ void pair_z(float ta, float tb, float th, float phi1, float phi2,
                                       float& zi, float& zj, float& zz) {
    float ca, sa, cb, sb, c, s;
    __sincosf(0.5f * ta, &sa, &ca);
    __sincosf(0.5f * tb, &sb, &cb);
    __sincosf(0.5f * th, &s, &c);
    float cp1 = __cosf(phi1);
    float cp2 = __cosf(phi2);

    float u = ca * sb, v = sa * cb;
    float p0 = ca * cb; p0 *= p0;
    float p3 = sa * sb; p3 *= p3;
    float u2 = u * u, v2 = v * v, c2 = c * c, s2 = s * s;
    float cs2uv = 2.0f * c * s * u * v;
    float p1 = c2 * u2 + s2 * v2 - cs2uv * cp1;
    float p2 = s2 * u2 + c2 * v2 + cs2uv * cp2;

    zi = p0 + p1 - p2 - p3;
    zj = p0 - p1 + p2 - p3;
    zz = p0 - p1 - p2 + p3;
}

__global__ void __launch_bounds__(BLOCK)
qfm_kernel(const float* __restrict__ x, float* __restrict__ out, int B) {
    int stride = gridDim.x * blockDim.x;
    for (int b = blockIdx.x * blockDim.x + threadIdx.x; b < B; b += stride) {
        // 10 floats per row, 8B-aligned (40*b bytes) -> 5x float2 loads
        const float2* xp = reinterpret_cast<const float2*>(x + (size_t)b * 10);
        float2 w0 = xp[0], w1 = xp[1], w2 = xp[2], w3 = xp[3], w4 = xp[4];

        float t0 = 0.5f * fast_tanh(w0.x);
        float t1 = 0.5f * fast_tanh(w0.y);
        float t2 = 0.5f * fast_tanh(w1.x);
        float t3 = 0.5f * fast_tanh(w1.y);
        float t4 = 0.5f * fast_tanh(w2.x);
        float t5 = 0.5f * fast_tanh(w2.y);
        float t6 = 0.5f * fast_tanh(w3.x);
        float t7 = 0.5f * fast_tanh(w3.y);
        float t8 = 0.5f * fast_tanh(w4.x);
        float t9 = 0.5f * fast_tanh(w4.y);

        float z0, z1, zz01, z2, z3, zz23;
        pair_z(t0, t1, t4, t5, t6, z0, z1, zz01);
        pair_z(t2, t3, t7, t8, t9, z2, z3, zz23);

        // out row: z0 z1 z2 z3 zz01 z0z2 z0z3 z1z2 z1z3 zz23
        float2* op = reinterpret_cast<float2*>(out + (size_t)b * 10);
        op[0] = make_float2(z0, z1);
        op[1] = make_float2(z2, z3);
        op[2] = make_float2(zz01, z0 * z2);
        op[3] = make_float2(z0 * z3, z1 * z2);
        op[4] = make_float2(z1 * z3, zz23);
    }
}

extern "C" void kernel_launch(void* const* d_in, const int* in_sizes, int n_in,
                              void* d_out, int out_size, void* d_ws, size_t ws_size,
                              hipStream_t stream) {
    const float* x = (const float*)d_in[0];
    float* out = (float*)d_out;
    int B = in_sizes[0] / 10;
    int blocks = (B + BLOCK - 1) / BLOCK;
    if (blocks > 2048) blocks = 2048;
    qfm_kernel<<<blocks, BLOCK, 0, stream>>>(x, out, B);
}